// Round 9
// baseline (10470.063 us; speedup 1.0000x reference)
//
#include <hip/hip_runtime.h>
#include <hip/hip_cooperative_groups.h>

namespace cg = cooperative_groups;

#define DEV __device__ __forceinline__
typedef unsigned short us;
typedef __bf16 bf8 __attribute__((ext_vector_type(8)));
typedef float  f4  __attribute__((ext_vector_type(4)));

DEV us f2bf(float f){
  unsigned int u = __builtin_bit_cast(unsigned int, f);
  u = u + 0x7fffu + ((u >> 16) & 1u);
  return (us)(u >> 16);
}
DEV float bf2f(us u){ unsigned int v = ((unsigned int)u) << 16; return __builtin_bit_cast(float, v); }
DEV float sigm(float x){ return 1.f/(1.f + __expf(-x)); }
DEV bf8 ldb(const us* p){ return *reinterpret_cast<const bf8*>(p); }
DEV f4 mfma(bf8 a, bf8 b, f4 c){ return __builtin_amdgcn_mfma_f32_16x16x32_bf16(a, b, c, 0, 0, 0); }

// ---------------- workspace layout (bytes) — total ~237 MB (<246.75 proven safe)
constexpr size_t OFF_WCAT0  = 0;                             // [2][1536][544] bf16 ([x32|h512] fused)
constexpr size_t OFF_WIH1   = OFF_WCAT0 + 2ull*1536*544*2;   // [1536][1024] bf16
constexpr size_t OFF_WHH1   = OFF_WIH1  + 1536ull*1024*2;    // [1536][512] bf16
constexpr size_t OFF_WIH1R  = OFF_WHH1  + 1536ull*512*2;     // [1536][1024] bf16
constexpr size_t OFF_FC1W   = OFF_WIH1R + 1536ull*1024*2;    // [256][1024] bf16
constexpr size_t OFF_FC2W   = OFF_FC1W  + 256ull*1024*2;     // [16][256] bf16
constexpr size_t OFF_BRZ0   = OFF_FC2W  + 16ull*256*2;       // [2][1024] f32
constexpr size_t OFF_BNIH0  = OFF_BRZ0  + 2*1024*4;          // [2][512]
constexpr size_t OFF_BNHH0  = OFF_BNIH0 + 2*512*4;           // [2][512]
constexpr size_t OFF_BRZ1   = OFF_BNHH0 + 2*512*4;           // [1024]
constexpr size_t OFF_BNIH1  = OFF_BRZ1  + 1024*4;            // [512]
constexpr size_t OFF_BNHH1  = OFF_BNIH1 + 512*4;             // [512]
constexpr size_t OFF_BRZ1R  = OFF_BNHH1 + 512*4;             // [1024]
constexpr size_t OFF_BNIH1R = OFF_BRZ1R + 1024*4;            // [512]
constexpr size_t OFF_BNHH1R = OFF_BNIH1R+ 512*4;             // [512]
constexpr size_t OFF_SC2    = OFF_BNHH1R+ 512*4;             // [256]
constexpr size_t OFF_SH2    = OFF_SC2   + 256*4;             // [256]
constexpr size_t OFF_FC2B   = OFF_SH2   + 256*4;             // [16]
constexpr size_t OFF_Y0B    = OFF_FC2B  + 64;                // [4096][28][512] bf16
constexpr size_t OFF_Y0FC   = OFF_Y0B   + 4096ull*28*512*2;  // [4096][4][512] bf16
constexpr size_t OFF_GX     = OFF_Y0FC  + 4096ull*4*512*2;   // [4][4096][1536] bf16
constexpr size_t OFF_H0BF   = OFF_GX    + 4ull*4096*1536*2;  // [2pp][4096][512] bf16
constexpr size_t OFF_H0F32  = OFF_H0BF  + 2ull*4096*512*2;   // [4096][512] f32
constexpr size_t OFF_H1BF   = OFF_H0F32 + 4096ull*512*4;     // [2pp][4096][512] bf16
constexpr size_t OFF_H1F32  = OFF_H1BF  + 2ull*4096*512*2;   // [4096][512] f32
constexpr size_t OFF_H1B    = OFF_H1F32 + 4096ull*512*4;     // [4096][512] bf16

constexpr long PPH   = 4096ll*512;
constexpr long PLANE = 4096ll*1536;

// ---------------- K0: weight/bias prep ----------------
__global__ void prep_kernel(
  const float* __restrict__ Wih0, const float* __restrict__ Whh0,
  const float* __restrict__ bih0, const float* __restrict__ bhh0,
  const float* __restrict__ Wih0r,const float* __restrict__ Whh0r,
  const float* __restrict__ bih0r,const float* __restrict__ bhh0r,
  const float* __restrict__ Wih1, const float* __restrict__ Whh1,
  const float* __restrict__ bih1, const float* __restrict__ bhh1,
  const float* __restrict__ Wih1r,const float* __restrict__ bih1r,
  const float* __restrict__ bhh1r,
  const float* __restrict__ fc1w, const float* __restrict__ fc1b,
  const float* __restrict__ gma,  const float* __restrict__ bta,
  const float* __restrict__ mean, const float* __restrict__ var,
  const float* __restrict__ fc2w, const float* __restrict__ fc2b,
  us* __restrict__ wcat0, us* __restrict__ wih1, us* __restrict__ whh1,
  us* __restrict__ wih1r, us* __restrict__ fc1wb, us* __restrict__ fc2wp,
  float* __restrict__ brz0, float* __restrict__ bnih0, float* __restrict__ bnhh0,
  float* __restrict__ brz1, float* __restrict__ bnih1, float* __restrict__ bnhh1,
  float* __restrict__ brz1r,float* __restrict__ bnih1r,float* __restrict__ bnhh1r,
  float* __restrict__ sc2,  float* __restrict__ sh2,   float* __restrict__ fc2bp)
{
  const int tid = blockIdx.x * blockDim.x + threadIdx.x;
  const int np  = gridDim.x * blockDim.x;
  // layer-0 fused: [dir][1536][544]; cols 0..27 W_ih, 28..31 pad, 32..543 W_hh
  for (int i = tid; i < 2*1536*544; i += np){
    int d = i / (1536*544); int rem = i - d*(1536*544);
    int n = rem / 544, k = rem - n*544;
    const float* ih = d ? Wih0r : Wih0;
    const float* hh = d ? Whh0r : Whh0;
    float v = (k < 32) ? (k < 28 ? ih[n*28 + k] : 0.f) : hh[n*512 + (k-32)];
    wcat0[i] = f2bf(v);
  }
  for (int i = tid; i < 1536*1024; i += np){
    wih1[i]  = f2bf(Wih1[i]);
    wih1r[i] = f2bf(Wih1r[i]);
  }
  for (int i = tid; i < 1536*512; i += np) whh1[i] = f2bf(Whh1[i]);
  for (int i = tid; i < 256*1024; i += np) fc1wb[i] = f2bf(fc1w[i]);
  for (int i = tid; i < 16*256;   i += np){
    int n = i / 256; fc2wp[i] = (n < 10) ? f2bf(fc2w[i]) : (us)0;
  }
  for (int i = tid; i < 1024; i += np){
    brz0[i]        = bih0[i]  + bhh0[i];
    brz0[1024 + i] = bih0r[i] + bhh0r[i];
    brz1[i]        = bih1[i]  + bhh1[i];
    brz1r[i]       = bih1r[i] + bhh1r[i];
  }
  for (int i = tid; i < 512; i += np){
    bnih0[i]       = bih0[1024 + i];   bnhh0[i]       = bhh0[1024 + i];
    bnih0[512 + i] = bih0r[1024 + i];  bnhh0[512 + i] = bhh0r[1024 + i];
    bnih1[i]       = bih1[1024 + i];   bnhh1[i]       = bhh1[1024 + i];
    bnih1r[i]      = bih1r[1024 + i];  bnhh1r[i]      = bhh1r[1024 + i];
  }
  for (int i = tid; i < 256; i += np){
    float s = gma[i] * rsqrtf(var[i] + 1e-5f);
    sc2[i] = s;
    sh2[i] = (fc1b[i] - mean[i]) * s + bta[i];
  }
  for (int i = tid; i < 16; i += np) fc2bp[i] = (i < 10) ? fc2b[i] : 0.f;
}

// ---------------- big GEMM: C = A @ B^T (bf16) ----------------
// A row R: m = R>>tshift, sl = R & mask; A = [seg0 (K0) | seg1 (K1)].
// B [1536][Kw]. Tile 128M x 128N; grid = nMtiles*12; mtile = bid % nMtiles.
// Pipeline: A LDS dbuf staged distance-2 (uA/vA regs); B regs distance-3
// (c/d/e named rotation, literal indices only — r4 spill bug avoided).
__global__ __launch_bounds__(512) void gemm_kernel(
  const us* __restrict__ s0, long s0m, long s0t, int K0,
  const us* __restrict__ s1, long s1m, long s1t, int K1,
  const us* __restrict__ B, int Kw, int nk, int tshift, int nMtiles,
  us* __restrict__ C, long cT)
{
  __shared__ us As[2*128*40];

  const int tid = threadIdx.x, bid = blockIdx.x;
  const int mtile = bid % nMtiles, ntile = bid / nMtiles;
  const int Mbase = mtile * 128, Nbase = ntile * 128;
  const int mask = (1 << tshift) - 1;

  const int w = tid >> 6, lane = tid & 63, ln = lane & 15, lq = lane >> 4;
  const int wm = w >> 2, wn = w & 3;
  const int srow = tid >> 2, sgrp = tid & 3;

  const us* pB0 = B + (size_t)(Nbase + wn*32 +  0 + ln) * Kw + lq*8;
  const us* pB1 = B + (size_t)(Nbase + wn*32 + 16 + ln) * Kw + lq*8;

  auto loadA = [&](int kt) -> uint4 {
    const int R = Mbase + srow;
    const int m = R >> tshift, sl = R & mask;
    const int col = kt*32 + sgrp*8;
    if (col < K0)
      return *reinterpret_cast<const uint4*>(s0 + (size_t)m*s0m + (long)sl*s0t + col);
    return *reinterpret_cast<const uint4*>(s1 + (size_t)m*s1m + (long)sl*s1t + (col - K0));
  };
  auto stA = [&](int buf, uint4 v){
    *reinterpret_cast<uint4*>(&As[buf + srow*40 + sgrp*8]) = v;
  };

  // prologue (nk >= 4 at all call sites)
  stA(0, loadA(0));
  uint4 uA = loadA(1), vA = loadA(2);
  bf8 c0 = ldb(pB0),      c1 = ldb(pB1);
  bf8 d0 = ldb(pB0 + 32), d1 = ldb(pB1 + 32);
  bf8 e0 = ldb(pB0 + 64), e1 = ldb(pB1 + 64);
  __syncthreads();

  f4 acc[4][2] = {};

  for (int kt = 0; kt < nk; ++kt){
    const int buf = (kt & 1) * 5120;
    bf8 a0 = ldb(&As[buf + (wm*64 +  0 + ln)*40 + lq*8]);
    bf8 a1 = ldb(&As[buf + (wm*64 + 16 + ln)*40 + lq*8]);
    bf8 a2 = ldb(&As[buf + (wm*64 + 32 + ln)*40 + lq*8]);
    bf8 a3 = ldb(&As[buf + (wm*64 + 48 + ln)*40 + lq*8]);
    acc[0][0] = mfma(a0, c0, acc[0][0]); acc[0][1] = mfma(a0, c1, acc[0][1]);
    acc[1][0] = mfma(a1, c0, acc[1][0]); acc[1][1] = mfma(a1, c1, acc[1][1]);
    acc[2][0] = mfma(a2, c0, acc[2][0]); acc[2][1] = mfma(a2, c1, acc[2][1]);
    acc[3][0] = mfma(a3, c0, acc[3][0]); acc[3][1] = mfma(a3, c1, acc[3][1]);
    if (kt + 1 < nk){
      stA(buf ^ 5120, uA);                 // chunk kt+1, loaded 2 iters ago
      uA = vA;
      vA = (kt + 3 < nk) ? loadA(kt + 3) : uint4{0,0,0,0};
      c0 = d0; c1 = d1; d0 = e0; d1 = e1;
      if (kt + 3 < nk){
        const int kc = (kt + 3) * 32;
        e0 = ldb(pB0 + kc); e1 = ldb(pB1 + kc);
      }
      __syncthreads();
    }
  }

  #pragma unroll
  for (int mtf = 0; mtf < 4; ++mtf){
    #pragma unroll
    for (int ntf = 0; ntf < 2; ++ntf){
      const int col = Nbase + wn*32 + ntf*16 + ln;
      #pragma unroll
      for (int e = 0; e < 4; ++e){
        const int R = Mbase + wm*64 + mtf*16 + lq*4 + e;
        const int m = R >> tshift, sl = R & mask;
        C[(size_t)sl*cT + (size_t)m*1536 + col] = f2bf(acc[mtf][ntf][e]);
      }
    }
  }
}

// ---------------- cooperative 4-step serial GRU ----------------
// grid 256 (= 16 hcb x 16 nm), 512 thr, 1 block/CU (147 KB LDS) -> co-resident.
// W slab (96 gate-rows x Kw) pinned in LDS ONCE; 4 recurrent steps with
// grid.sync() between. l0: Kw=544, nk=17, kxn=1 (x folded as chunk 0, XN split);
// l1: Kw=512, nk=16, kxn=0 (gx supplies input projection).
__global__ void gru_serial4_kernel(
  const us* __restrict__ W, int Kw, int nk, int kxn,
  const float* __restrict__ xbase, long xstep,
  const us* __restrict__ gx4,
  us* __restrict__ hpp, float* __restrict__ hF,
  us* __restrict__ ybase, long ymstride, long ytstep,
  const float* __restrict__ brz, const float* __restrict__ bni,
  const float* __restrict__ bnh, int s0)
{
  __shared__ us Ws[96*552];       // pitch 552 (544 max + 8)
  __shared__ us As[2*256*40];

  cg::grid_group grid = cg::this_grid();

  const int tid = threadIdx.x, bid = blockIdx.x;
  const int hcb = bid >> 4, nm = bid & 15;   // co-XCD for same nm (bid%8 = nm%8)
  const size_t Mbase = (size_t)nm * 256;
  const int hcBase = hcb * 32;
  const int KX = kxn * 32;

  const int w = tid >> 6, lane = tid & 63, ln = lane & 15, lq = lane >> 4;

  // ---- W slab -> LDS (once per 4 steps)
  {
    const int nsg = Kw >> 3;
    for (int q = tid; q < 96*nsg; q += 512){
      const int rl = q / nsg, sg = q - rl*nsg;
      const int grow = (rl >> 5)*512 + hcBase + (rl & 31);
      *reinterpret_cast<uint4*>(&Ws[rl*552 + sg*8]) =
        *reinterpret_cast<const uint4*>(&W[(size_t)grow*Kw + sg*8]);
    }
  }
  __syncthreads();

  for (int sl = 0; sl < 4; ++sl){
    const int s = s0 + sl;
    const int first = (s == 0);
    const us* hIn  = hpp + (s & 1)*PPH;
    us*       hOut = hpp + ((s & 1) ^ 1)*PPH;
    const float* xb = xbase ? (xbase + (long)sl*xstep) : nullptr;
    const us* gxp   = gx4 ? (gx4 + (size_t)sl*PLANE) : nullptr;
    us*       yp    = ybase ? (ybase + (long)sl*ytstep) : nullptr;

    auto ldA = [&](int kt, int q) -> uint4 {
      const int row = q >> 2, grp = q & 3;
      const size_t m = Mbase + row;
      const int col = kt*32 + grp*8;
      if (col < KX){
        const float* xr = xb + m*784;
        us t8[8];
        #pragma unroll
        for (int j = 0; j < 8; ++j){
          int cc = col + j;
          t8[j] = (cc < 28) ? f2bf(xr[cc]) : (us)0;
        }
        return *reinterpret_cast<uint4*>(t8);
      }
      if (first) return uint4{0,0,0,0};
      return *reinterpret_cast<const uint4*>(&hIn[m*512 + (col - KX)]);
    };
    auto stA = [&](int buf, int q, uint4 v){
      const int row = q >> 2, grp = q & 3;
      *reinterpret_cast<uint4*>(&As[buf + row*40 + grp*8]) = v;
    };

    f4 acc[3][2][2] = {};            // [gate][nt][mt]
    f4 accXN[2][2] = {};

    // prologue: chunk0 -> LDS; chunks 1,2 -> regs (distance-2)
    stA(0, tid, ldA(0, tid)); stA(0, tid + 512, ldA(0, tid + 512));
    uint4 s1a = ldA(1, tid), s1b = ldA(1, tid + 512);
    uint4 s2a = ldA(2, tid), s2b = ldA(2, tid + 512);
    __syncthreads();

    for (int kt = 0; kt < nk; ++kt){
      const int buf = (kt & 1) * 10240;
      bf8 a0 = ldb(&As[buf + (w*32 +  0 + ln)*40 + lq*8]);
      bf8 a1 = ldb(&As[buf + (w*32 + 16 + ln)*40 + lq*8]);
      const int kc = kt*32 + lq*8;
      #pragma unroll
      for (int g = 0; g < 3; ++g){
        #pragma unroll
        for (int nt = 0; nt < 2; ++nt){
          bf8 b = ldb(&Ws[(g*32 + nt*16 + ln)*552 + kc]);
          acc[g][nt][0] = mfma(a0, b, acc[g][nt][0]);
          acc[g][nt][1] = mfma(a1, b, acc[g][nt][1]);
        }
      }
      if (kt == kxn - 1){               // capture gx_n (x part) for the n-gate
        #pragma unroll
        for (int nt = 0; nt < 2; ++nt){
          accXN[nt][0] = acc[2][nt][0]; accXN[nt][1] = acc[2][nt][1];
          acc[2][nt][0] = f4{0.f,0.f,0.f,0.f}; acc[2][nt][1] = f4{0.f,0.f,0.f,0.f};
        }
      }
      if (kt + 1 < nk){
        stA(buf ^ 10240, tid, s1a); stA(buf ^ 10240, tid + 512, s1b);
        s1a = s2a; s1b = s2b;
        if (kt + 3 < nk){ s2a = ldA(kt + 3, tid); s2b = ldA(kt + 3, tid + 512); }
        __syncthreads();
      }
    }

    // ---- gate epilogue
    #pragma unroll
    for (int nt = 0; nt < 2; ++nt){
      const int ch = hcBase + nt*16 + ln;
      const float br = brz[ch], bz = brz[512 + ch], bi = bni[ch], bh = bnh[ch];
      #pragma unroll
      for (int mt = 0; mt < 2; ++mt){
        #pragma unroll
        for (int e = 0; e < 4; ++e){
          const size_t m = Mbase + w*32 + mt*16 + lq*4 + e;
          float r, z, n;
          if (gxp){
            const us* gxr = gxp + m*1536;
            r = sigm(acc[0][nt][mt][e] + bf2f(gxr[ch])       + br);
            z = sigm(acc[1][nt][mt][e] + bf2f(gxr[512 + ch]) + bz);
            n = tanhf(bf2f(gxr[1024 + ch]) + bi + r*(acc[2][nt][mt][e] + bh));
          } else {
            r = sigm(acc[0][nt][mt][e] + br);
            z = sigm(acc[1][nt][mt][e] + bz);
            n = tanhf(accXN[nt][mt][e] + bi + r*(acc[2][nt][mt][e] + bh));
          }
          float hprev = first ? 0.f : hF[m*512 + ch];
          float h = (1.f - z)*n + z*hprev;
          hF[m*512 + ch] = h;
          us hb = f2bf(h);
          hOut[m*512 + ch] = hb;
          if (yp) yp[m*ymstride + ch] = hb;
        }
      }
    }

    if (sl < 3){
      __threadfence();
      grid.sync();
    }
  }
}

// ---------------- l1 backward single step: elementwise gates from gxb (h=0) ----
__global__ void gate1b_kernel(
  const us* __restrict__ gxb, const float* __restrict__ brz,
  const float* __restrict__ bni, const float* __restrict__ bnh,
  us* __restrict__ h1b)
{
  const int i = blockIdx.x * blockDim.x + threadIdx.x;
  if (i >= 4096*512) return;
  const int m = i >> 9, ch = i & 511;
  const us* g = gxb + (size_t)m*1536;
  float r = sigm(bf2f(g[ch]) + brz[ch]);
  float z = sigm(bf2f(g[512 + ch]) + brz[512 + ch]);
  float n = tanhf(bf2f(g[1024 + ch]) + bni[ch] + r*bnh[ch]);
  h1b[i] = f2bf((1.f - z)*n);
}

// ---------------- head: [h1f|h1b] -> fc1 -> bn/relu -> fc2 -> log_softmax ----
__global__ __launch_bounds__(512) void head_kernel(
  const us* __restrict__ h1f, const us* __restrict__ h1b,
  const us* __restrict__ fc1w, const us* __restrict__ fc2wp,
  const float* __restrict__ sc2, const float* __restrict__ sh2,
  const float* __restrict__ fc2b, float* __restrict__ out)
{
  constexpr int APS = 1048;
  __shared__ us As[32 * APS];
  __shared__ us actS[32 * 264];
  __shared__ float lg[32 * 16];
  const int tid = threadIdx.x;
  const size_t row0 = (size_t)blockIdx.x * 32;
  const int w = tid >> 6, lane = tid & 63, ln = lane & 15, lq = lane >> 4;

  for (int i = tid; i < 32*128; i += 512){
    int r = i >> 7, g = i & 127, col = g*8;
    uint4 v = (col < 512)
      ? *reinterpret_cast<const uint4*>(h1f + (row0 + r)*512 + col)
      : *reinterpret_cast<const uint4*>(h1b + (row0 + r)*512 + (col - 512));
    *reinterpret_cast<uint4*>(&As[r*APS + col]) = v;
  }
  __syncthreads();

  {
    f4 acc[2][2] = {};
    for (int kt = 0; kt < 32; ++kt){
      const int kc = kt*32 + lq*8;
      bf8 a0 = ldb(&As[ln*APS + kc]);
      bf8 a1 = ldb(&As[(16 + ln)*APS + kc]);
      #pragma unroll
      for (int nt = 0; nt < 2; ++nt){
        const int col = w*32 + nt*16 + ln;
        bf8 b = ldb(&fc1w[(size_t)col*1024 + kc]);
        acc[0][nt] = mfma(a0, b, acc[0][nt]);
        acc[1][nt] = mfma(a1, b, acc[1][nt]);
      }
    }
    #pragma unroll
    for (int nt = 0; nt < 2; ++nt){
      const int col = w*32 + nt*16 + ln;
      const float sc = sc2[col], sh = sh2[col];
      #pragma unroll
      for (int mt = 0; mt < 2; ++mt)
        #pragma unroll
        for (int e = 0; e < 4; ++e){
          float v = fmaxf(acc[mt][nt][e]*sc + sh, 0.f);
          actS[(mt*16 + lq*4 + e)*264 + col] = f2bf(v);
        }
    }
    __syncthreads();
  }

  if (w == 0){
    f4 acc[2] = {};
    for (int kt = 0; kt < 8; ++kt){
      const int kc = kt*32 + lq*8;
      bf8 a0 = ldb(&actS[ln*264 + kc]);
      bf8 a1 = ldb(&actS[(16 + ln)*264 + kc]);
      bf8 b  = ldb(&fc2wp[ln*256 + kc]);
      acc[0] = mfma(a0, b, acc[0]);
      acc[1] = mfma(a1, b, acc[1]);
    }
    const float bb = fc2b[ln];
    #pragma unroll
    for (int mt = 0; mt < 2; ++mt)
      #pragma unroll
      for (int e = 0; e < 4; ++e)
        lg[(mt*16 + lq*4 + e)*16 + ln] = acc[mt][e] + bb;
  }
  __syncthreads();
  if (tid < 32){
    const int r = tid;
    float mx = -1e30f;
    for (int cc = 0; cc < 10; ++cc) mx = fmaxf(mx, lg[r*16 + cc]);
    float sum = 0.f;
    for (int cc = 0; cc < 10; ++cc) sum += __expf(lg[r*16 + cc] - mx);
    const float lse = mx + logf(sum);
    for (int cc = 0; cc < 10; ++cc)
      out[(row0 + r)*10 + cc] = lg[r*16 + cc] - lse;
  }
}

// ---------------- cooperative launch helper ----------------
static void launch_serial4(hipStream_t stream,
  const us* W, int Kw, int nk, int kxn,
  const float* xbase, long xstep, const us* gx4,
  us* hpp, float* hF,
  us* ybase, long ymstride, long ytstep,
  const float* brz, const float* bni, const float* bnh, int s0)
{
  void* args[] = { &W, &Kw, &nk, &kxn, &xbase, &xstep, &gx4, &hpp, &hF,
                   &ybase, &ymstride, &ytstep, &brz, &bni, &bnh, &s0 };
  hipLaunchCooperativeKernel((void*)gru_serial4_kernel, dim3(256), dim3(512),
                             args, 0, stream);
}

// ---------------- launch ----------------
extern "C" void kernel_launch(void* const* d_in, const int* in_sizes, int n_in,
                              void* d_out, int out_size, void* d_ws, size_t ws_size,
                              hipStream_t stream)
{
  (void)in_sizes; (void)n_in; (void)out_size; (void)ws_size;
  char* ws = (char*)d_ws;
  auto US = [&](size_t off){ return (us*)(ws + off); };
  auto FP = [&](size_t off){ return (float*)(ws + off); };

  const float* x      = (const float*)d_in[0];
  const float* Wih0   = (const float*)d_in[1];
  const float* Whh0   = (const float*)d_in[2];
  const float* bih0   = (const float*)d_in[3];
  const float* bhh0   = (const float*)d_in[4];
  const float* Wih0r  = (const float*)d_in[5];
  const float* Whh0r  = (const float*)d_in[6];
  const float* bih0r  = (const float*)d_in[7];
  const float* bhh0r  = (const float*)d_in[8];
  const float* Wih1   = (const float*)d_in[9];
  const float* Whh1   = (const float*)d_in[10];
  const float* bih1   = (const float*)d_in[11];
  const float* bhh1   = (const float*)d_in[12];
  const float* Wih1r  = (const float*)d_in[13];
  // d_in[14] (W_hh_l1r) unused: backward layer-1 runs exactly one step from h=0.
  const float* bih1r  = (const float*)d_in[15];
  const float* bhh1r  = (const float*)d_in[16];
  const float* fc1w   = (const float*)d_in[17];
  const float* fc1b   = (const float*)d_in[18];
  const float* gma    = (const float*)d_in[19];
  const float* bta    = (const float*)d_in[20];
  const float* mean   = (const float*)d_in[21];
  const float* var    = (const float*)d_in[22];
  const float* fc2w   = (const float*)d_in[23];
  const float* fc2b   = (const float*)d_in[24];

  prep_kernel<<<512, 256, 0, stream>>>(
    Wih0, Whh0, bih0, bhh0, Wih0r, Whh0r, bih0r, bhh0r,
    Wih1, Whh1, bih1, bhh1, Wih1r, bih1r, bhh1r,
    fc1w, fc1b, gma, bta, mean, var, fc2w, fc2b,
    US(OFF_WCAT0), US(OFF_WIH1), US(OFF_WHH1), US(OFF_WIH1R),
    US(OFF_FC1W), US(OFF_FC2W),
    FP(OFF_BRZ0), FP(OFF_BNIH0), FP(OFF_BNHH0),
    FP(OFF_BRZ1), FP(OFF_BNIH1), FP(OFF_BNHH1),
    FP(OFF_BRZ1R), FP(OFF_BNIH1R), FP(OFF_BNHH1R),
    FP(OFF_SC2), FP(OFF_SH2), FP(OFF_FC2B));

  us* y0b  = US(OFF_Y0B);
  us* y0fc = US(OFF_Y0FC);
  us* gx   = US(OFF_GX);
  us* h0bf = US(OFF_H0BF);
  us* h1bf = US(OFF_H1BF);

  // ---- phase A: layer-0 backward, 7 cooperative 4-step launches ----
  for (int c = 0; c < 7; ++c){
    const int t0 = 27 - 4*c;
    launch_serial4(stream,
      US(OFF_WCAT0) + 1536ll*544, 544, 17, 1,
      x + t0*28, -28, nullptr,
      h0bf, FP(OFF_H0F32),
      y0b + (long)t0*512, 28ll*512, -512,
      FP(OFF_BRZ0) + 1024, FP(OFF_BNIH0) + 512, FP(OFF_BNHH0) + 512, 4*c);
  }

  // ---- phase B: l0 fwd (coop) -> gx1 GEMM -> l1 fwd (coop), per 4-step chunk ----
  for (int c = 0; c < 7; ++c){
    const int t0 = 4*c;
    launch_serial4(stream,
      US(OFF_WCAT0), 544, 17, 1,
      x + t0*28, 28, nullptr,
      h0bf, FP(OFF_H0F32),
      y0fc, 4ll*512, 512,
      FP(OFF_BRZ0), FP(OFF_BNIH0), FP(OFF_BNHH0), 4*c);

    gemm_kernel<<<128*12, 512, 0, stream>>>(
      y0fc, 4ll*512, 512, 512,
      y0b + (long)t0*512, 28ll*512, 512, 512,
      US(OFF_WIH1), 1024, 32, 2, 128, gx, PLANE);

    launch_serial4(stream,
      US(OFF_WHH1), 512, 16, 0,
      nullptr, 0, gx,
      h1bf, FP(OFF_H1F32),
      nullptr, 0, 0,
      FP(OFF_BRZ1), FP(OFF_BNIH1), FP(OFF_BNHH1), 4*c);
  }

  // ---- layer-1 backward: gxb = [h0f_27 | y0b_27] @ Wih1r^T, then gates (h=0) ----
  gemm_kernel<<<32*12, 512, 0, stream>>>(
    h0bf, 512, 0, 512,                       // h0f final state = pp plane 0
    y0b + 27ll*512, 28ll*512, 0, 512,
    US(OFF_WIH1R), 1024, 32, 0, 32, gx, 0);
  gate1b_kernel<<<8192, 256, 0, stream>>>(
    gx, FP(OFF_BRZ1R), FP(OFF_BNIH1R), FP(OFF_BNHH1R), US(OFF_H1B));

  // ---- head (h1f final = pp plane 0 after 28 steps) ----
  head_kernel<<<128, 512, 0, stream>>>(
    h1bf, US(OFF_H1B), US(OFF_FC1W), US(OFF_FC2W),
    FP(OFF_SC2), FP(OFF_SH2), FP(OFF_FC2B), (float*)d_out);
}

// Round 10
// 8547.842 us; speedup vs baseline: 1.2249x; 1.2249x over previous
//
#include <hip/hip_runtime.h>
#include <hip/hip_cooperative_groups.h>

namespace cg = cooperative_groups;

#define DEV __device__ __forceinline__
typedef unsigned short us;
typedef __bf16 bf8 __attribute__((ext_vector_type(8)));
typedef float  f4  __attribute__((ext_vector_type(4)));

DEV us f2bf(float f){
  unsigned int u = __builtin_bit_cast(unsigned int, f);
  u = u + 0x7fffu + ((u >> 16) & 1u);
  return (us)(u >> 16);
}
DEV float bf2f(us u){ unsigned int v = ((unsigned int)u) << 16; return __builtin_bit_cast(float, v); }
DEV float sigm(float x){ return 1.f/(1.f + __expf(-x)); }
DEV bf8 ldb(const us* p){ return *reinterpret_cast<const bf8*>(p); }
DEV f4 mfma(bf8 a, bf8 b, f4 c){ return __builtin_amdgcn_mfma_f32_16x16x32_bf16(a, b, c, 0, 0, 0); }

// ---------------- workspace layout (bytes) — total ~237 MB (<246.75 proven safe)
constexpr size_t OFF_WCAT0  = 0;                             // [2][1536][544] bf16 ([x32|h512] fused)
constexpr size_t OFF_WIH1   = OFF_WCAT0 + 2ull*1536*544*2;   // [1536][1024] bf16
constexpr size_t OFF_WHH1   = OFF_WIH1  + 1536ull*1024*2;    // [1536][512] bf16
constexpr size_t OFF_WIH1R  = OFF_WHH1  + 1536ull*512*2;     // [1536][1024] bf16
constexpr size_t OFF_FC1W   = OFF_WIH1R + 1536ull*1024*2;    // [256][1024] bf16
constexpr size_t OFF_FC2W   = OFF_FC1W  + 256ull*1024*2;     // [16][256] bf16
constexpr size_t OFF_BRZ0   = OFF_FC2W  + 16ull*256*2;       // [2][1024] f32
constexpr size_t OFF_BNIH0  = OFF_BRZ0  + 2*1024*4;          // [2][512]
constexpr size_t OFF_BNHH0  = OFF_BNIH0 + 2*512*4;           // [2][512]
constexpr size_t OFF_BRZ1   = OFF_BNHH0 + 2*512*4;           // [1024]
constexpr size_t OFF_BNIH1  = OFF_BRZ1  + 1024*4;            // [512]
constexpr size_t OFF_BNHH1  = OFF_BNIH1 + 512*4;             // [512]
constexpr size_t OFF_BRZ1R  = OFF_BNHH1 + 512*4;             // [1024]
constexpr size_t OFF_BNIH1R = OFF_BRZ1R + 1024*4;            // [512]
constexpr size_t OFF_BNHH1R = OFF_BNIH1R+ 512*4;             // [512]
constexpr size_t OFF_SC2    = OFF_BNHH1R+ 512*4;             // [256]
constexpr size_t OFF_SH2    = OFF_SC2   + 256*4;             // [256]
constexpr size_t OFF_FC2B   = OFF_SH2   + 256*4;             // [16]
constexpr size_t OFF_Y0B    = OFF_FC2B  + 64;                // [4096][28][512] bf16
constexpr size_t OFF_Y0FC   = OFF_Y0B   + 4096ull*28*512*2;  // [4096][4][512] bf16
constexpr size_t OFF_GX     = OFF_Y0FC  + 4096ull*4*512*2;   // [4][4096][1536] bf16
constexpr size_t OFF_H0BF   = OFF_GX    + 4ull*4096*1536*2;  // [2pp][4096][512] bf16
constexpr size_t OFF_H0F32  = OFF_H0BF  + 2ull*4096*512*2;   // [4096][512] f32
constexpr size_t OFF_H1BF   = OFF_H0F32 + 4096ull*512*4;     // [2pp][4096][512] bf16
constexpr size_t OFF_H1F32  = OFF_H1BF  + 2ull*4096*512*2;   // [4096][512] f32
constexpr size_t OFF_H1B    = OFF_H1F32 + 4096ull*512*4;     // [4096][512] bf16

constexpr long PPH   = 4096ll*512;
constexpr long PLANE = 4096ll*1536;

// ---------------- K0: weight/bias prep ----------------
__global__ void prep_kernel(
  const float* __restrict__ Wih0, const float* __restrict__ Whh0,
  const float* __restrict__ bih0, const float* __restrict__ bhh0,
  const float* __restrict__ Wih0r,const float* __restrict__ Whh0r,
  const float* __restrict__ bih0r,const float* __restrict__ bhh0r,
  const float* __restrict__ Wih1, const float* __restrict__ Whh1,
  const float* __restrict__ bih1, const float* __restrict__ bhh1,
  const float* __restrict__ Wih1r,const float* __restrict__ bih1r,
  const float* __restrict__ bhh1r,
  const float* __restrict__ fc1w, const float* __restrict__ fc1b,
  const float* __restrict__ gma,  const float* __restrict__ bta,
  const float* __restrict__ mean, const float* __restrict__ var,
  const float* __restrict__ fc2w, const float* __restrict__ fc2b,
  us* __restrict__ wcat0, us* __restrict__ wih1, us* __restrict__ whh1,
  us* __restrict__ wih1r, us* __restrict__ fc1wb, us* __restrict__ fc2wp,
  float* __restrict__ brz0, float* __restrict__ bnih0, float* __restrict__ bnhh0,
  float* __restrict__ brz1, float* __restrict__ bnih1, float* __restrict__ bnhh1,
  float* __restrict__ brz1r,float* __restrict__ bnih1r,float* __restrict__ bnhh1r,
  float* __restrict__ sc2,  float* __restrict__ sh2,   float* __restrict__ fc2bp)
{
  const int tid = blockIdx.x * blockDim.x + threadIdx.x;
  const int np  = gridDim.x * blockDim.x;
  // layer-0 fused: [dir][1536][544]; cols 0..27 W_ih, 28..31 pad, 32..543 W_hh
  for (int i = tid; i < 2*1536*544; i += np){
    int d = i / (1536*544); int rem = i - d*(1536*544);
    int n = rem / 544, k = rem - n*544;
    const float* ih = d ? Wih0r : Wih0;
    const float* hh = d ? Whh0r : Whh0;
    float v = (k < 32) ? (k < 28 ? ih[n*28 + k] : 0.f) : hh[n*512 + (k-32)];
    wcat0[i] = f2bf(v);
  }
  for (int i = tid; i < 1536*1024; i += np){
    wih1[i]  = f2bf(Wih1[i]);
    wih1r[i] = f2bf(Wih1r[i]);
  }
  for (int i = tid; i < 1536*512; i += np) whh1[i] = f2bf(Whh1[i]);
  for (int i = tid; i < 256*1024; i += np) fc1wb[i] = f2bf(fc1w[i]);
  for (int i = tid; i < 16*256;   i += np){
    int n = i / 256; fc2wp[i] = (n < 10) ? f2bf(fc2w[i]) : (us)0;
  }
  for (int i = tid; i < 1024; i += np){
    brz0[i]        = bih0[i]  + bhh0[i];
    brz0[1024 + i] = bih0r[i] + bhh0r[i];
    brz1[i]        = bih1[i]  + bhh1[i];
    brz1r[i]       = bih1r[i] + bhh1r[i];
  }
  for (int i = tid; i < 512; i += np){
    bnih0[i]       = bih0[1024 + i];   bnhh0[i]       = bhh0[1024 + i];
    bnih0[512 + i] = bih0r[1024 + i];  bnhh0[512 + i] = bhh0r[1024 + i];
    bnih1[i]       = bih1[1024 + i];   bnhh1[i]       = bhh1[1024 + i];
    bnih1r[i]      = bih1r[1024 + i];  bnhh1r[i]      = bhh1r[1024 + i];
  }
  for (int i = tid; i < 256; i += np){
    float s = gma[i] * rsqrtf(var[i] + 1e-5f);
    sc2[i] = s;
    sh2[i] = (fc1b[i] - mean[i]) * s + bta[i];
  }
  for (int i = tid; i < 16; i += np) fc2bp[i] = (i < 10) ? fc2b[i] : 0.f;
}

// ---------------- big GEMM: C = A @ B^T (bf16) ----------------
// A row R: m = R>>tshift, sl = R & mask; A = [seg0 (K0) | seg1 (K1)].
// B [1536][Kw]. Tile 128M x 128N; grid = nMtiles*12; mtile = bid % nMtiles.
// Pipeline: A LDS dbuf staged distance-2 (uA/vA regs); B regs distance-3
// (c/d/e named rotation, literal indices only — r4 spill bug avoided).
__global__ __launch_bounds__(512) void gemm_kernel(
  const us* __restrict__ s0, long s0m, long s0t, int K0,
  const us* __restrict__ s1, long s1m, long s1t, int K1,
  const us* __restrict__ B, int Kw, int nk, int tshift, int nMtiles,
  us* __restrict__ C, long cT)
{
  __shared__ us As[2*128*40];

  const int tid = threadIdx.x, bid = blockIdx.x;
  const int mtile = bid % nMtiles, ntile = bid / nMtiles;
  const int Mbase = mtile * 128, Nbase = ntile * 128;
  const int mask = (1 << tshift) - 1;

  const int w = tid >> 6, lane = tid & 63, ln = lane & 15, lq = lane >> 4;
  const int wm = w >> 2, wn = w & 3;
  const int srow = tid >> 2, sgrp = tid & 3;

  const us* pB0 = B + (size_t)(Nbase + wn*32 +  0 + ln) * Kw + lq*8;
  const us* pB1 = B + (size_t)(Nbase + wn*32 + 16 + ln) * Kw + lq*8;

  auto loadA = [&](int kt) -> uint4 {
    const int R = Mbase + srow;
    const int m = R >> tshift, sl = R & mask;
    const int col = kt*32 + sgrp*8;
    if (col < K0)
      return *reinterpret_cast<const uint4*>(s0 + (size_t)m*s0m + (long)sl*s0t + col);
    return *reinterpret_cast<const uint4*>(s1 + (size_t)m*s1m + (long)sl*s1t + (col - K0));
  };
  auto stA = [&](int buf, uint4 v){
    *reinterpret_cast<uint4*>(&As[buf + srow*40 + sgrp*8]) = v;
  };

  // prologue (nk >= 4 at all call sites)
  stA(0, loadA(0));
  uint4 uA = loadA(1), vA = loadA(2);
  bf8 c0 = ldb(pB0),      c1 = ldb(pB1);
  bf8 d0 = ldb(pB0 + 32), d1 = ldb(pB1 + 32);
  bf8 e0 = ldb(pB0 + 64), e1 = ldb(pB1 + 64);
  __syncthreads();

  f4 acc[4][2] = {};

  for (int kt = 0; kt < nk; ++kt){
    const int buf = (kt & 1) * 5120;
    bf8 a0 = ldb(&As[buf + (wm*64 +  0 + ln)*40 + lq*8]);
    bf8 a1 = ldb(&As[buf + (wm*64 + 16 + ln)*40 + lq*8]);
    bf8 a2 = ldb(&As[buf + (wm*64 + 32 + ln)*40 + lq*8]);
    bf8 a3 = ldb(&As[buf + (wm*64 + 48 + ln)*40 + lq*8]);
    acc[0][0] = mfma(a0, c0, acc[0][0]); acc[0][1] = mfma(a0, c1, acc[0][1]);
    acc[1][0] = mfma(a1, c0, acc[1][0]); acc[1][1] = mfma(a1, c1, acc[1][1]);
    acc[2][0] = mfma(a2, c0, acc[2][0]); acc[2][1] = mfma(a2, c1, acc[2][1]);
    acc[3][0] = mfma(a3, c0, acc[3][0]); acc[3][1] = mfma(a3, c1, acc[3][1]);
    if (kt + 1 < nk){
      stA(buf ^ 5120, uA);                 // chunk kt+1, loaded 2 iters ago
      uA = vA;
      vA = (kt + 3 < nk) ? loadA(kt + 3) : uint4{0,0,0,0};
      c0 = d0; c1 = d1; d0 = e0; d1 = e1;
      if (kt + 3 < nk){
        const int kc = (kt + 3) * 32;
        e0 = ldb(pB0 + kc); e1 = ldb(pB1 + kc);
      }
      __syncthreads();
    }
  }

  #pragma unroll
  for (int mtf = 0; mtf < 4; ++mtf){
    #pragma unroll
    for (int ntf = 0; ntf < 2; ++ntf){
      const int col = Nbase + wn*32 + ntf*16 + ln;
      #pragma unroll
      for (int e = 0; e < 4; ++e){
        const int R = Mbase + wm*64 + mtf*16 + lq*4 + e;
        const int m = R >> tshift, sl = R & mask;
        C[(size_t)sl*cT + (size_t)m*1536 + col] = f2bf(acc[mtf][ntf][e]);
      }
    }
  }
}

// ---------------- cooperative 4-step serial GRU ----------------
// grid 256 (= 16 hcb x 16 nm), 512 thr, 1 block/CU (147 KB LDS) -> co-resident.
// W slab (96 gate-rows x Kw) pinned in LDS ONCE; 4 recurrent steps with
// grid.sync() between. l0: Kw=544, nk=17, kxn=1 (x folded as chunk 0, XN split);
// l1: Kw=512, nk=16, kxn=0 (gx supplies input projection).
// __launch_bounds__(512) is MANDATORY: without it HIP assumes 1024-thread
// blocks -> 64-VGPR cap -> K-loop scratch spill (r9: 125 MB WRITE_SIZE/dispatch,
// 441 us vs predicted ~60; same class of bug as r4/r5).
__global__ __launch_bounds__(512) void gru_serial4_kernel(
  const us* __restrict__ W, int Kw, int nk, int kxn,
  const float* __restrict__ xbase, long xstep,
  const us* __restrict__ gx4,
  us* __restrict__ hpp, float* __restrict__ hF,
  us* __restrict__ ybase, long ymstride, long ytstep,
  const float* __restrict__ brz, const float* __restrict__ bni,
  const float* __restrict__ bnh, int s0)
{
  __shared__ us Ws[96*552];       // pitch 552 (544 max + 8)
  __shared__ us As[2*256*40];

  cg::grid_group grid = cg::this_grid();

  const int tid = threadIdx.x, bid = blockIdx.x;
  const int hcb = bid >> 4, nm = bid & 15;   // co-XCD for same nm (bid%8 = nm%8)
  const size_t Mbase = (size_t)nm * 256;
  const int hcBase = hcb * 32;
  const int KX = kxn * 32;

  const int w = tid >> 6, lane = tid & 63, ln = lane & 15, lq = lane >> 4;

  // ---- W slab -> LDS (once per 4 steps)
  {
    const int nsg = Kw >> 3;
    for (int q = tid; q < 96*nsg; q += 512){
      const int rl = q / nsg, sg = q - rl*nsg;
      const int grow = (rl >> 5)*512 + hcBase + (rl & 31);
      *reinterpret_cast<uint4*>(&Ws[rl*552 + sg*8]) =
        *reinterpret_cast<const uint4*>(&W[(size_t)grow*Kw + sg*8]);
    }
  }
  __syncthreads();

  for (int sl = 0; sl < 4; ++sl){
    const int s = s0 + sl;
    const int first = (s == 0);
    const us* hIn  = hpp + (s & 1)*PPH;
    us*       hOut = hpp + ((s & 1) ^ 1)*PPH;
    const float* xb = xbase ? (xbase + (long)sl*xstep) : nullptr;
    const us* gxp   = gx4 ? (gx4 + (size_t)sl*PLANE) : nullptr;
    us*       yp    = ybase ? (ybase + (long)sl*ytstep) : nullptr;

    auto ldA = [&](int kt, int q) -> uint4 {
      const int row = q >> 2, grp = q & 3;
      const size_t m = Mbase + row;
      const int col = kt*32 + grp*8;
      if (col < KX){
        const float* xr = xb + m*784;
        us t8[8];
        #pragma unroll
        for (int j = 0; j < 8; ++j){
          int cc = col + j;
          t8[j] = (cc < 28) ? f2bf(xr[cc]) : (us)0;
        }
        return *reinterpret_cast<uint4*>(t8);
      }
      if (first) return uint4{0,0,0,0};
      return *reinterpret_cast<const uint4*>(&hIn[m*512 + (col - KX)]);
    };
    auto stA = [&](int buf, int q, uint4 v){
      const int row = q >> 2, grp = q & 3;
      *reinterpret_cast<uint4*>(&As[buf + row*40 + grp*8]) = v;
    };

    f4 acc[3][2][2] = {};            // [gate][nt][mt]
    f4 accXN[2][2] = {};

    // prologue: chunk0 -> LDS; chunks 1,2 -> regs (distance-2)
    stA(0, tid, ldA(0, tid)); stA(0, tid + 512, ldA(0, tid + 512));
    uint4 s1a = ldA(1, tid), s1b = ldA(1, tid + 512);
    uint4 s2a = ldA(2, tid), s2b = ldA(2, tid + 512);
    __syncthreads();

    for (int kt = 0; kt < nk; ++kt){
      const int buf = (kt & 1) * 10240;
      bf8 a0 = ldb(&As[buf + (w*32 +  0 + ln)*40 + lq*8]);
      bf8 a1 = ldb(&As[buf + (w*32 + 16 + ln)*40 + lq*8]);
      const int kc = kt*32 + lq*8;
      #pragma unroll
      for (int g = 0; g < 3; ++g){
        #pragma unroll
        for (int nt = 0; nt < 2; ++nt){
          bf8 b = ldb(&Ws[(g*32 + nt*16 + ln)*552 + kc]);
          acc[g][nt][0] = mfma(a0, b, acc[g][nt][0]);
          acc[g][nt][1] = mfma(a1, b, acc[g][nt][1]);
        }
      }
      if (kt == kxn - 1){               // capture gx_n (x part) for the n-gate
        #pragma unroll
        for (int nt = 0; nt < 2; ++nt){
          accXN[nt][0] = acc[2][nt][0]; accXN[nt][1] = acc[2][nt][1];
          acc[2][nt][0] = f4{0.f,0.f,0.f,0.f}; acc[2][nt][1] = f4{0.f,0.f,0.f,0.f};
        }
      }
      if (kt + 1 < nk){
        stA(buf ^ 10240, tid, s1a); stA(buf ^ 10240, tid + 512, s1b);
        s1a = s2a; s1b = s2b;
        if (kt + 3 < nk){ s2a = ldA(kt + 3, tid); s2b = ldA(kt + 3, tid + 512); }
        __syncthreads();
      }
    }

    // ---- gate epilogue
    #pragma unroll
    for (int nt = 0; nt < 2; ++nt){
      const int ch = hcBase + nt*16 + ln;
      const float br = brz[ch], bz = brz[512 + ch], bi = bni[ch], bh = bnh[ch];
      #pragma unroll
      for (int mt = 0; mt < 2; ++mt){
        #pragma unroll
        for (int e = 0; e < 4; ++e){
          const size_t m = Mbase + w*32 + mt*16 + lq*4 + e;
          float r, z, n;
          if (gxp){
            const us* gxr = gxp + m*1536;
            r = sigm(acc[0][nt][mt][e] + bf2f(gxr[ch])       + br);
            z = sigm(acc[1][nt][mt][e] + bf2f(gxr[512 + ch]) + bz);
            n = tanhf(bf2f(gxr[1024 + ch]) + bi + r*(acc[2][nt][mt][e] + bh));
          } else {
            r = sigm(acc[0][nt][mt][e] + br);
            z = sigm(acc[1][nt][mt][e] + bz);
            n = tanhf(accXN[nt][mt][e] + bi + r*(acc[2][nt][mt][e] + bh));
          }
          float hprev = first ? 0.f : hF[m*512 + ch];
          float h = (1.f - z)*n + z*hprev;
          hF[m*512 + ch] = h;
          us hb = f2bf(h);
          hOut[m*512 + ch] = hb;
          if (yp) yp[m*ymstride + ch] = hb;
        }
      }
    }

    if (sl < 3){
      __threadfence();
      grid.sync();
    }
  }
}

// ---------------- l1 backward single step: elementwise gates from gxb (h=0) ----
__global__ void gate1b_kernel(
  const us* __restrict__ gxb, const float* __restrict__ brz,
  const float* __restrict__ bni, const float* __restrict__ bnh,
  us* __restrict__ h1b)
{
  const int i = blockIdx.x * blockDim.x + threadIdx.x;
  if (i >= 4096*512) return;
  const int m = i >> 9, ch = i & 511;
  const us* g = gxb + (size_t)m*1536;
  float r = sigm(bf2f(g[ch]) + brz[ch]);
  float z = sigm(bf2f(g[512 + ch]) + brz[512 + ch]);
  float n = tanhf(bf2f(g[1024 + ch]) + bni[ch] + r*bnh[ch]);
  h1b[i] = f2bf((1.f - z)*n);
}

// ---------------- head: [h1f|h1b] -> fc1 -> bn/relu -> fc2 -> log_softmax ----
__global__ __launch_bounds__(512) void head_kernel(
  const us* __restrict__ h1f, const us* __restrict__ h1b,
  const us* __restrict__ fc1w, const us* __restrict__ fc2wp,
  const float* __restrict__ sc2, const float* __restrict__ sh2,
  const float* __restrict__ fc2b, float* __restrict__ out)
{
  constexpr int APS = 1048;
  __shared__ us As[32 * APS];
  __shared__ us actS[32 * 264];
  __shared__ float lg[32 * 16];
  const int tid = threadIdx.x;
  const size_t row0 = (size_t)blockIdx.x * 32;
  const int w = tid >> 6, lane = tid & 63, ln = lane & 15, lq = lane >> 4;

  for (int i = tid; i < 32*128; i += 512){
    int r = i >> 7, g = i & 127, col = g*8;
    uint4 v = (col < 512)
      ? *reinterpret_cast<const uint4*>(h1f + (row0 + r)*512 + col)
      : *reinterpret_cast<const uint4*>(h1b + (row0 + r)*512 + (col - 512));
    *reinterpret_cast<uint4*>(&As[r*APS + col]) = v;
  }
  __syncthreads();

  {
    f4 acc[2][2] = {};
    for (int kt = 0; kt < 32; ++kt){
      const int kc = kt*32 + lq*8;
      bf8 a0 = ldb(&As[ln*APS + kc]);
      bf8 a1 = ldb(&As[(16 + ln)*APS + kc]);
      #pragma unroll
      for (int nt = 0; nt < 2; ++nt){
        const int col = w*32 + nt*16 + ln;
        bf8 b = ldb(&fc1w[(size_t)col*1024 + kc]);
        acc[0][nt] = mfma(a0, b, acc[0][nt]);
        acc[1][nt] = mfma(a1, b, acc[1][nt]);
      }
    }
    #pragma unroll
    for (int nt = 0; nt < 2; ++nt){
      const int col = w*32 + nt*16 + ln;
      const float sc = sc2[col], sh = sh2[col];
      #pragma unroll
      for (int mt = 0; mt < 2; ++mt)
        #pragma unroll
        for (int e = 0; e < 4; ++e){
          float v = fmaxf(acc[mt][nt][e]*sc + sh, 0.f);
          actS[(mt*16 + lq*4 + e)*264 + col] = f2bf(v);
        }
    }
    __syncthreads();
  }

  if (w == 0){
    f4 acc[2] = {};
    for (int kt = 0; kt < 8; ++kt){
      const int kc = kt*32 + lq*8;
      bf8 a0 = ldb(&actS[ln*264 + kc]);
      bf8 a1 = ldb(&actS[(16 + ln)*264 + kc]);
      bf8 b  = ldb(&fc2wp[ln*256 + kc]);
      acc[0] = mfma(a0, b, acc[0]);
      acc[1] = mfma(a1, b, acc[1]);
    }
    const float bb = fc2b[ln];
    #pragma unroll
    for (int mt = 0; mt < 2; ++mt)
      #pragma unroll
      for (int e = 0; e < 4; ++e)
        lg[(mt*16 + lq*4 + e)*16 + ln] = acc[mt][e] + bb;
  }
  __syncthreads();
  if (tid < 32){
    const int r = tid;
    float mx = -1e30f;
    for (int cc = 0; cc < 10; ++cc) mx = fmaxf(mx, lg[r*16 + cc]);
    float sum = 0.f;
    for (int cc = 0; cc < 10; ++cc) sum += __expf(lg[r*16 + cc] - mx);
    const float lse = mx + logf(sum);
    for (int cc = 0; cc < 10; ++cc)
      out[(row0 + r)*10 + cc] = lg[r*16 + cc] - lse;
  }
}

// ---------------- cooperative launch helper ----------------
static void launch_serial4(hipStream_t stream,
  const us* W, int Kw, int nk, int kxn,
  const float* xbase, long xstep, const us* gx4,
  us* hpp, float* hF,
  us* ybase, long ymstride, long ytstep,
  const float* brz, const float* bni, const float* bnh, int s0)
{
  void* args[] = { &W, &Kw, &nk, &kxn, &xbase, &xstep, &gx4, &hpp, &hF,
                   &ybase, &ymstride, &ytstep, &brz, &bni, &bnh, &s0 };
  hipLaunchCooperativeKernel((void*)gru_serial4_kernel, dim3(256), dim3(512),
                             args, 0, stream);
}

// ---------------- launch ----------------
extern "C" void kernel_launch(void* const* d_in, const int* in_sizes, int n_in,
                              void* d_out, int out_size, void* d_ws, size_t ws_size,
                              hipStream_t stream)
{
  (void)in_sizes; (void)n_in; (void)out_size; (void)ws_size;
  char* ws = (char*)d_ws;
  auto US = [&](size_t off){ return (us*)(ws + off); };
  auto FP = [&](size_t off){ return (float*)(ws + off); };

  const float* x      = (const float*)d_in[0];
  const float* Wih0   = (const float*)d_in[1];
  const float* Whh0   = (const float*)d_in[2];
  const float* bih0   = (const float*)d_in[3];
  const float* bhh0   = (const float*)d_in[4];
  const float* Wih0r  = (const float*)d_in[5];
  const float* Whh0r  = (const float*)d_in[6];
  const float* bih0r  = (const float*)d_in[7];
  const float* bhh0r  = (const float*)d_in[8];
  const float* Wih1   = (const float*)d_in[9];
  const float* Whh1   = (const float*)d_in[10];
  const float* bih1   = (const float*)d_in[11];
  const float* bhh1   = (const float*)d_in[12];
  const float* Wih1r  = (const float*)d_in[13];
  // d_in[14] (W_hh_l1r) unused: backward layer-1 runs exactly one step from h=0.
  const float* bih1r  = (const float*)d_in[15];
  const float* bhh1r  = (const float*)d_in[16];
  const float* fc1w   = (const float*)d_in[17];
  const float* fc1b   = (const float*)d_in[18];
  const float* gma    = (const float*)d_in[19];
  const float* bta    = (const float*)d_in[20];
  const float* mean   = (const float*)d_in[21];
  const float* var    = (const float*)d_in[22];
  const float* fc2w   = (const float*)d_in[23];
  const float* fc2b   = (const float*)d_in[24];

  prep_kernel<<<512, 256, 0, stream>>>(
    Wih0, Whh0, bih0, bhh0, Wih0r, Whh0r, bih0r, bhh0r,
    Wih1, Whh1, bih1, bhh1, Wih1r, bih1r, bhh1r,
    fc1w, fc1b, gma, bta, mean, var, fc2w, fc2b,
    US(OFF_WCAT0), US(OFF_WIH1), US(OFF_WHH1), US(OFF_WIH1R),
    US(OFF_FC1W), US(OFF_FC2W),
    FP(OFF_BRZ0), FP(OFF_BNIH0), FP(OFF_BNHH0),
    FP(OFF_BRZ1), FP(OFF_BNIH1), FP(OFF_BNHH1),
    FP(OFF_BRZ1R), FP(OFF_BNIH1R), FP(OFF_BNHH1R),
    FP(OFF_SC2), FP(OFF_SH2), FP(OFF_FC2B));

  us* y0b  = US(OFF_Y0B);
  us* y0fc = US(OFF_Y0FC);
  us* gx   = US(OFF_GX);
  us* h0bf = US(OFF_H0BF);
  us* h1bf = US(OFF_H1BF);

  // ---- phase A: layer-0 backward, 7 cooperative 4-step launches ----
  for (int c = 0; c < 7; ++c){
    const int t0 = 27 - 4*c;
    launch_serial4(stream,
      US(OFF_WCAT0) + 1536ll*544, 544, 17, 1,
      x + t0*28, -28, nullptr,
      h0bf, FP(OFF_H0F32),
      y0b + (long)t0*512, 28ll*512, -512,
      FP(OFF_BRZ0) + 1024, FP(OFF_BNIH0) + 512, FP(OFF_BNHH0) + 512, 4*c);
  }

  // ---- phase B: l0 fwd (coop) -> gx1 GEMM -> l1 fwd (coop), per 4-step chunk ----
  for (int c = 0; c < 7; ++c){
    const int t0 = 4*c;
    launch_serial4(stream,
      US(OFF_WCAT0), 544, 17, 1,
      x + t0*28, 28, nullptr,
      h0bf, FP(OFF_H0F32),
      y0fc, 4ll*512, 512,
      FP(OFF_BRZ0), FP(OFF_BNIH0), FP(OFF_BNHH0), 4*c);

    gemm_kernel<<<128*12, 512, 0, stream>>>(
      y0fc, 4ll*512, 512, 512,
      y0b + (long)t0*512, 28ll*512, 512, 512,
      US(OFF_WIH1), 1024, 32, 2, 128, gx, PLANE);

    launch_serial4(stream,
      US(OFF_WHH1), 512, 16, 0,
      nullptr, 0, gx,
      h1bf, FP(OFF_H1F32),
      nullptr, 0, 0,
      FP(OFF_BRZ1), FP(OFF_BNIH1), FP(OFF_BNHH1), 4*c);
  }

  // ---- layer-1 backward: gxb = [h0f_27 | y0b_27] @ Wih1r^T, then gates (h=0) ----
  gemm_kernel<<<32*12, 512, 0, stream>>>(
    h0bf, 512, 0, 512,                       // h0f final state = pp plane 0
    y0b + 27ll*512, 28ll*512, 0, 512,
    US(OFF_WIH1R), 1024, 32, 0, 32, gx, 0);
  gate1b_kernel<<<8192, 256, 0, stream>>>(
    gx, FP(OFF_BRZ1R), FP(OFF_BNIH1R), FP(OFF_BNHH1R), US(OFF_H1B));

  // ---- head (h1f final = pp plane 0 after 28 steps) ----
  head_kernel<<<128, 512, 0, stream>>>(
    h1bf, US(OFF_H1B), US(OFF_FC1W), US(OFF_FC2W),
    FP(OFF_SC2), FP(OFF_SH2), FP(OFF_FC2B), (float*)d_out);
}

// Round 11
// 7552.226 us; speedup vs baseline: 1.3864x; 1.1318x over previous
//
#include <hip/hip_runtime.h>

#define DEV __device__ __forceinline__
typedef unsigned short us;
typedef __bf16 bf8 __attribute__((ext_vector_type(8)));
typedef float  f4  __attribute__((ext_vector_type(4)));

DEV us f2bf(float f){
  unsigned int u = __builtin_bit_cast(unsigned int, f);
  u = u + 0x7fffu + ((u >> 16) & 1u);
  return (us)(u >> 16);
}
DEV float bf2f(us u){ unsigned int v = ((unsigned int)u) << 16; return __builtin_bit_cast(float, v); }
DEV float sigm(float x){ return 1.f/(1.f + __expf(-x)); }
DEV bf8 ldb(const us* p){ return *reinterpret_cast<const bf8*>(p); }
DEV f4 mfma(bf8 a, bf8 b, f4 c){ return __builtin_amdgcn_mfma_f32_16x16x32_bf16(a, b, c, 0, 0, 0); }

// ---------------- workspace layout (bytes) — total ~237 MB (<246.75 proven safe)
constexpr size_t OFF_WCAT0  = 0;                             // [2][1536][544] bf16 ([x32|h512])
constexpr size_t OFF_WIH1   = OFF_WCAT0 + 2ull*1536*544*2;   // [1536][1024] bf16
constexpr size_t OFF_WHH1   = OFF_WIH1  + 1536ull*1024*2;    // [1536][512] bf16
constexpr size_t OFF_WIH1R  = OFF_WHH1  + 1536ull*512*2;     // [1536][1024] bf16
constexpr size_t OFF_FC1W   = OFF_WIH1R + 1536ull*1024*2;    // [256][1024] bf16
constexpr size_t OFF_FC2W   = OFF_FC1W  + 256ull*1024*2;     // [16][256] bf16
constexpr size_t OFF_BRZ0   = OFF_FC2W  + 16ull*256*2;       // [2][1024] f32
constexpr size_t OFF_BNIH0  = OFF_BRZ0  + 2*1024*4;          // [2][512]
constexpr size_t OFF_BNHH0  = OFF_BNIH0 + 2*512*4;           // [2][512]
constexpr size_t OFF_BRZ1   = OFF_BNHH0 + 2*512*4;           // [1024]
constexpr size_t OFF_BNIH1  = OFF_BRZ1  + 1024*4;            // [512]
constexpr size_t OFF_BNHH1  = OFF_BNIH1 + 512*4;             // [512]
constexpr size_t OFF_BRZ1R  = OFF_BNHH1 + 512*4;             // [1024]
constexpr size_t OFF_BNIH1R = OFF_BRZ1R + 1024*4;            // [512]
constexpr size_t OFF_BNHH1R = OFF_BNIH1R+ 512*4;             // [512]
constexpr size_t OFF_SC2    = OFF_BNHH1R+ 512*4;             // [256]
constexpr size_t OFF_SH2    = OFF_SC2   + 256*4;             // [256]
constexpr size_t OFF_FC2B   = OFF_SH2   + 256*4;             // [16]
constexpr size_t OFF_Y0B    = OFF_FC2B  + 64;                // [4096][28][512] bf16
constexpr size_t OFF_Y0FC   = OFF_Y0B   + 4096ull*28*512*2;  // [4096][4][512] bf16
constexpr size_t OFF_GX     = OFF_Y0FC  + 4096ull*4*512*2;   // [4][4096][1536] bf16
constexpr size_t OFF_H0BF   = OFF_GX    + 4ull*4096*1536*2;  // [2pp][4096][512] bf16
constexpr size_t OFF_H0F32  = OFF_H0BF  + 2ull*4096*512*2;   // [4096][512] f32
constexpr size_t OFF_H1BF   = OFF_H0F32 + 4096ull*512*4;     // [2pp][4096][512] bf16
constexpr size_t OFF_H1F32  = OFF_H1BF  + 2ull*4096*512*2;   // [4096][512] f32
constexpr size_t OFF_H1B    = OFF_H1F32 + 4096ull*512*4;     // [4096][512] bf16
constexpr size_t OFF_FLAGS  = OFF_H1B   + 4096ull*512*2;     // [3][28][16] u32

constexpr long PPH   = 4096ll*512;
constexpr long PLANE = 4096ll*1536;
constexpr int  NFLAGS = 3*28*16;

// ---------------- flag zeroing (re-run every call; ws is re-poisoned) ---------
__global__ void zeroflags_kernel(unsigned int* __restrict__ f){
  int i = blockIdx.x*blockDim.x + threadIdx.x;
  if (i < NFLAGS) f[i] = 0u;
}

// ---------------- K0: weight/bias prep ----------------
__global__ void prep_kernel(
  const float* __restrict__ Wih0, const float* __restrict__ Whh0,
  const float* __restrict__ bih0, const float* __restrict__ bhh0,
  const float* __restrict__ Wih0r,const float* __restrict__ Whh0r,
  const float* __restrict__ bih0r,const float* __restrict__ bhh0r,
  const float* __restrict__ Wih1, const float* __restrict__ Whh1,
  const float* __restrict__ bih1, const float* __restrict__ bhh1,
  const float* __restrict__ Wih1r,const float* __restrict__ bih1r,
  const float* __restrict__ bhh1r,
  const float* __restrict__ fc1w, const float* __restrict__ fc1b,
  const float* __restrict__ gma,  const float* __restrict__ bta,
  const float* __restrict__ mean, const float* __restrict__ var,
  const float* __restrict__ fc2w, const float* __restrict__ fc2b,
  us* __restrict__ wcat0, us* __restrict__ wih1, us* __restrict__ whh1,
  us* __restrict__ wih1r, us* __restrict__ fc1wb, us* __restrict__ fc2wp,
  float* __restrict__ brz0, float* __restrict__ bnih0, float* __restrict__ bnhh0,
  float* __restrict__ brz1, float* __restrict__ bnih1, float* __restrict__ bnhh1,
  float* __restrict__ brz1r,float* __restrict__ bnih1r,float* __restrict__ bnhh1r,
  float* __restrict__ sc2,  float* __restrict__ sh2,   float* __restrict__ fc2bp)
{
  const int tid = blockIdx.x * blockDim.x + threadIdx.x;
  const int np  = gridDim.x * blockDim.x;
  // layer-0 fused: [dir][1536][544]; cols 0..27 W_ih, 28..31 pad, 32..543 W_hh
  for (int i = tid; i < 2*1536*544; i += np){
    int d = i / (1536*544); int rem = i - d*(1536*544);
    int n = rem / 544, k = rem - n*544;
    const float* ih = d ? Wih0r : Wih0;
    const float* hh = d ? Whh0r : Whh0;
    float v = (k < 32) ? (k < 28 ? ih[n*28 + k] : 0.f) : hh[n*512 + (k-32)];
    wcat0[i] = f2bf(v);
  }
  for (int i = tid; i < 1536*1024; i += np){
    wih1[i]  = f2bf(Wih1[i]);
    wih1r[i] = f2bf(Wih1r[i]);
  }
  for (int i = tid; i < 1536*512; i += np) whh1[i] = f2bf(Whh1[i]);
  for (int i = tid; i < 256*1024; i += np) fc1wb[i] = f2bf(fc1w[i]);
  for (int i = tid; i < 16*256;   i += np){
    int n = i / 256; fc2wp[i] = (n < 10) ? f2bf(fc2w[i]) : (us)0;
  }
  for (int i = tid; i < 1024; i += np){
    brz0[i]        = bih0[i]  + bhh0[i];
    brz0[1024 + i] = bih0r[i] + bhh0r[i];
    brz1[i]        = bih1[i]  + bhh1[i];
    brz1r[i]       = bih1r[i] + bhh1r[i];
  }
  for (int i = tid; i < 512; i += np){
    bnih0[i]       = bih0[1024 + i];   bnhh0[i]       = bhh0[1024 + i];
    bnih0[512 + i] = bih0r[1024 + i];  bnhh0[512 + i] = bhh0r[1024 + i];
    bnih1[i]       = bih1[1024 + i];   bnhh1[i]       = bhh1[1024 + i];
    bnih1r[i]      = bih1r[1024 + i];  bnhh1r[i]      = bhh1r[1024 + i];
  }
  for (int i = tid; i < 256; i += np){
    float s = gma[i] * rsqrtf(var[i] + 1e-5f);
    sc2[i] = s;
    sh2[i] = (fc1b[i] - mean[i]) * s + bta[i];
  }
  for (int i = tid; i < 16; i += np) fc2bp[i] = (i < 10) ? fc2b[i] : 0.f;
}

// ---------------- big GEMM: C = A @ B^T (bf16) — r8-proven structure ----------
__global__ __launch_bounds__(512) void gemm_kernel(
  const us* __restrict__ s0, long s0m, long s0t, int K0,
  const us* __restrict__ s1, long s1m, long s1t, int K1,
  const us* __restrict__ B, int Kw, int nk, int tshift, int nMtiles,
  us* __restrict__ C, long cT)
{
  __shared__ us As[2*128*40];

  const int tid = threadIdx.x, bid = blockIdx.x;
  const int mtile = bid % nMtiles, ntile = bid / nMtiles;
  const int Mbase = mtile * 128, Nbase = ntile * 128;
  const int mask = (1 << tshift) - 1;

  const int w = tid >> 6, lane = tid & 63, ln = lane & 15, lq = lane >> 4;
  const int wm = w >> 2, wn = w & 3;
  const int srow = tid >> 2, sgrp = tid & 3;

  const us* pB0 = B + (size_t)(Nbase + wn*32 +  0 + ln) * Kw + lq*8;
  const us* pB1 = B + (size_t)(Nbase + wn*32 + 16 + ln) * Kw + lq*8;

  auto loadA = [&](int kt) -> uint4 {
    const int R = Mbase + srow;
    const int m = R >> tshift, sl = R & mask;
    const int col = kt*32 + sgrp*8;
    if (col < K0)
      return *reinterpret_cast<const uint4*>(s0 + (size_t)m*s0m + (long)sl*s0t + col);
    return *reinterpret_cast<const uint4*>(s1 + (size_t)m*s1m + (long)sl*s1t + (col - K0));
  };
  auto stA = [&](int buf, uint4 v){
    *reinterpret_cast<uint4*>(&As[buf + srow*40 + sgrp*8]) = v;
  };

  stA(0, loadA(0));
  uint4 uA = loadA(1), vA = loadA(2);
  bf8 c0 = ldb(pB0),      c1 = ldb(pB1);
  bf8 d0 = ldb(pB0 + 32), d1 = ldb(pB1 + 32);
  bf8 e0 = ldb(pB0 + 64), e1 = ldb(pB1 + 64);
  __syncthreads();

  f4 acc[4][2] = {};

  for (int kt = 0; kt < nk; ++kt){
    const int buf = (kt & 1) * 5120;
    bf8 a0 = ldb(&As[buf + (wm*64 +  0 + ln)*40 + lq*8]);
    bf8 a1 = ldb(&As[buf + (wm*64 + 16 + ln)*40 + lq*8]);
    bf8 a2 = ldb(&As[buf + (wm*64 + 32 + ln)*40 + lq*8]);
    bf8 a3 = ldb(&As[buf + (wm*64 + 48 + ln)*40 + lq*8]);
    acc[0][0] = mfma(a0, c0, acc[0][0]); acc[0][1] = mfma(a0, c1, acc[0][1]);
    acc[1][0] = mfma(a1, c0, acc[1][0]); acc[1][1] = mfma(a1, c1, acc[1][1]);
    acc[2][0] = mfma(a2, c0, acc[2][0]); acc[2][1] = mfma(a2, c1, acc[2][1]);
    acc[3][0] = mfma(a3, c0, acc[3][0]); acc[3][1] = mfma(a3, c1, acc[3][1]);
    if (kt + 1 < nk){
      stA(buf ^ 5120, uA);
      uA = vA;
      vA = (kt + 3 < nk) ? loadA(kt + 3) : uint4{0,0,0,0};
      c0 = d0; c1 = d1; d0 = e0; d1 = e1;
      if (kt + 3 < nk){
        const int kc = (kt + 3) * 32;
        e0 = ldb(pB0 + kc); e1 = ldb(pB1 + kc);
      }
      __syncthreads();
    }
  }

  #pragma unroll
  for (int mtf = 0; mtf < 4; ++mtf){
    #pragma unroll
    for (int ntf = 0; ntf < 2; ++ntf){
      const int col = Nbase + wn*32 + ntf*16 + ln;
      #pragma unroll
      for (int e = 0; e < 4; ++e){
        const int R = Mbase + wm*64 + mtf*16 + lq*4 + e;
        const int m = R >> tshift, sl = R & mask;
        C[(size_t)sl*cT + (size_t)m*1536 + col] = f2bf(acc[mtf][ntf][e]);
      }
    }
  }
}

// ---------------- multi-step serial GRU chain ----------------
// Coop-launched (co-residency ONLY — no grid.sync: r10 showed full grid.sync
// costs ~25-30us each). grid 256 = 16 hcb x 16 nm; block (nm,hcb) owns rows
// [nm*256,+256) x hc cols [hcb*32,+32). Cross-step dependency is ONLY within
// the 16-block nm-group (co-XCD: bid%8 = nm%8) -> per-nm flag barrier via
// agent-scope atomics. W slab pinned in LDS once. A-fragments streamed
// per-wave directly from L2 (exact MFMA A-layout, 16B/lane) — NO K-loop
// barriers, fully unrolled. __launch_bounds__(512) MANDATORY (r9: without it,
// 64-VGPR cap -> scratch spill).
__global__ __launch_bounds__(512) void gru_chain_kernel(
  const us* __restrict__ W, int Kw, int KX,
  const float* __restrict__ xbase, long xtstep,
  const us* __restrict__ gx4,
  us* __restrict__ hpp, float* __restrict__ hF,
  us* __restrict__ ybase, long ymstride, long ytstep,
  const float* __restrict__ brz, const float* __restrict__ bni,
  const float* __restrict__ bnh, int s0, int nsteps,
  unsigned int* __restrict__ flags)
{
  __shared__ us Ws[96*520];     // h-part: 96 gate-rows x 512 (pad->520)
  __shared__ us Wx[96*32];      // x-part (l0 only)

  const int tid = threadIdx.x, bid = blockIdx.x;
  const int hcb = bid >> 4, nm = bid & 15;
  const size_t Mbase = (size_t)nm * 256;
  const int hcBase = hcb * 32;
  const int w = tid >> 6, lane = tid & 63, ln = lane & 15, lq = lane >> 4;

  // ---- W slab -> LDS (once per launch)
  for (int q = tid; q < 96*64; q += 512){
    const int rl = q >> 6, sg = q & 63;
    const int grow = (rl >> 5)*512 + hcBase + (rl & 31);
    *reinterpret_cast<uint4*>(&Ws[rl*520 + sg*8]) =
      *reinterpret_cast<const uint4*>(&W[(size_t)grow*Kw + KX + sg*8]);
  }
  if (KX){
    for (int q = tid; q < 96*4; q += 512){
      const int rl = q >> 2, sg = q & 3;
      const int grow = (rl >> 5)*512 + hcBase + (rl & 31);
      *reinterpret_cast<uint4*>(&Wx[rl*32 + sg*8]) =
        *reinterpret_cast<const uint4*>(&W[(size_t)grow*Kw + sg*8]);
    }
  }
  __syncthreads();

  const size_t m0 = Mbase + w*32 + ln;   // A rows: m0 (mt 0), m0+16 (mt 1)

  for (int sl = 0; sl < nsteps; ++sl){
    const int s = s0 + sl;
    const int first = (s == 0);
    const us* hIn  = hpp + (s & 1)*PPH;
    us*       hOut = hpp + ((s & 1) ^ 1)*PPH;

    f4 acc[3][2][2] = {};        // [gate][nt][mt]
    f4 accXN[2][2] = {};

    if (KX){
      // ---- x chunk (cols 0..31 of A, fp32 source)
      const float* xr = xbase + (long)sl*xtstep;
      us t8[8];
      const float* r0 = xr + m0*784;
      #pragma unroll
      for (int j = 0; j < 8; ++j){
        int cc = lq*8 + j; t8[j] = (cc < 28) ? f2bf(r0[cc]) : (us)0;
      }
      bf8 a0 = *reinterpret_cast<bf8*>(t8);
      const float* r1 = xr + (m0 + 16)*784;
      #pragma unroll
      for (int j = 0; j < 8; ++j){
        int cc = lq*8 + j; t8[j] = (cc < 28) ? f2bf(r1[cc]) : (us)0;
      }
      bf8 a1 = *reinterpret_cast<bf8*>(t8);
      #pragma unroll
      for (int g = 0; g < 3; ++g){
        #pragma unroll
        for (int nt = 0; nt < 2; ++nt){
          bf8 b = ldb(&Wx[(g*32 + nt*16 + ln)*32 + lq*8]);
          acc[g][nt][0] = mfma(a0, b, acc[g][nt][0]);
          acc[g][nt][1] = mfma(a1, b, acc[g][nt][1]);
        }
      }
      // capture gx_n (x part of n-gate); n-gate h-part restarts at zero
      #pragma unroll
      for (int nt = 0; nt < 2; ++nt){
        accXN[nt][0] = acc[2][nt][0]; accXN[nt][1] = acc[2][nt][1];
        acc[2][nt][0] = f4{0.f,0.f,0.f,0.f}; acc[2][nt][1] = f4{0.f,0.f,0.f,0.f};
      }
    }

    if (!first){
      // ---- h chunks: 16 iterations, barrier-free, A direct from L2
      #pragma unroll
      for (int kt = 0; kt < 16; ++kt){
        const us* hr = hIn + kt*32 + lq*8;
        bf8 a0 = ldb(hr + m0*512);
        bf8 a1 = ldb(hr + (m0 + 16)*512);
        const int kc = kt*32 + lq*8;
        #pragma unroll
        for (int g = 0; g < 3; ++g){
          #pragma unroll
          for (int nt = 0; nt < 2; ++nt){
            bf8 b = ldb(&Ws[(g*32 + nt*16 + ln)*520 + kc]);
            acc[g][nt][0] = mfma(a0, b, acc[g][nt][0]);
            acc[g][nt][1] = mfma(a1, b, acc[g][nt][1]);
          }
        }
      }
    }

    // ---- gate epilogue
    const us* gxp = gx4 ? (gx4 + (size_t)sl*PLANE) : nullptr;
    us* yp = ybase ? (ybase + (long)sl*ytstep) : nullptr;
    #pragma unroll
    for (int nt = 0; nt < 2; ++nt){
      const int ch = hcBase + nt*16 + ln;
      const float br = brz[ch], bz = brz[512 + ch], bi = bni[ch], bh = bnh[ch];
      #pragma unroll
      for (int mt = 0; mt < 2; ++mt){
        #pragma unroll
        for (int e = 0; e < 4; ++e){
          const size_t m = Mbase + w*32 + mt*16 + lq*4 + e;
          float r, z, n;
          if (gxp){
            const us* gxr = gxp + m*1536;
            r = sigm(acc[0][nt][mt][e] + bf2f(gxr[ch])       + br);
            z = sigm(acc[1][nt][mt][e] + bf2f(gxr[512 + ch]) + bz);
            n = tanhf(bf2f(gxr[1024 + ch]) + bi + r*(acc[2][nt][mt][e] + bh));
          } else {
            r = sigm(acc[0][nt][mt][e] + br);
            z = sigm(acc[1][nt][mt][e] + bz);
            n = tanhf(accXN[nt][mt][e] + bi + r*(acc[2][nt][mt][e] + bh));
          }
          float hprev = first ? 0.f : hF[m*512 + ch];
          float h = (1.f - z)*n + z*hprev;
          hF[m*512 + ch] = h;
          us hb = f2bf(h);
          hOut[m*512 + ch] = hb;
          if (yp) yp[m*ymstride + ch] = hb;
        }
      }
    }

    // ---- per-nm 16-block barrier (skip after last step of this launch)
    if (sl + 1 < nsteps){
      __threadfence();
      __syncthreads();
      if (tid == 0){
        unsigned int* f = flags + (unsigned)s*16 + nm;
        __hip_atomic_fetch_add(f, 1u, __ATOMIC_RELEASE, __HIP_MEMORY_SCOPE_AGENT);
        while (__hip_atomic_load(f, __ATOMIC_ACQUIRE, __HIP_MEMORY_SCOPE_AGENT) < 16u) {}
      }
      __syncthreads();
    }
  }
}

// ---------------- l1 backward single step: elementwise gates from gxb (h=0) ----
__global__ void gate1b_kernel(
  const us* __restrict__ gxb, const float* __restrict__ brz,
  const float* __restrict__ bni, const float* __restrict__ bnh,
  us* __restrict__ h1b)
{
  const int i = blockIdx.x * blockDim.x + threadIdx.x;
  if (i >= 4096*512) return;
  const int m = i >> 9, ch = i & 511;
  const us* g = gxb + (size_t)m*1536;
  float r = sigm(bf2f(g[ch]) + brz[ch]);
  float z = sigm(bf2f(g[512 + ch]) + brz[512 + ch]);
  float n = tanhf(bf2f(g[1024 + ch]) + bni[ch] + r*bnh[ch]);
  h1b[i] = f2bf((1.f - z)*n);
}

// ---------------- head: [h1f|h1b] -> fc1 -> bn/relu -> fc2 -> log_softmax ----
__global__ __launch_bounds__(512) void head_kernel(
  const us* __restrict__ h1f, const us* __restrict__ h1b,
  const us* __restrict__ fc1w, const us* __restrict__ fc2wp,
  const float* __restrict__ sc2, const float* __restrict__ sh2,
  const float* __restrict__ fc2b, float* __restrict__ out)
{
  constexpr int APS = 1048;
  __shared__ us As[32 * APS];
  __shared__ us actS[32 * 264];
  __shared__ float lg[32 * 16];
  const int tid = threadIdx.x;
  const size_t row0 = (size_t)blockIdx.x * 32;
  const int w = tid >> 6, lane = tid & 63, ln = lane & 15, lq = lane >> 4;

  for (int i = tid; i < 32*128; i += 512){
    int r = i >> 7, g = i & 127, col = g*8;
    uint4 v = (col < 512)
      ? *reinterpret_cast<const uint4*>(h1f + (row0 + r)*512 + col)
      : *reinterpret_cast<const uint4*>(h1b + (row0 + r)*512 + (col - 512));
    *reinterpret_cast<uint4*>(&As[r*APS + col]) = v;
  }
  __syncthreads();

  {
    f4 acc[2][2] = {};
    for (int kt = 0; kt < 32; ++kt){
      const int kc = kt*32 + lq*8;
      bf8 a0 = ldb(&As[ln*APS + kc]);
      bf8 a1 = ldb(&As[(16 + ln)*APS + kc]);
      #pragma unroll
      for (int nt = 0; nt < 2; ++nt){
        const int col = w*32 + nt*16 + ln;
        bf8 b = ldb(&fc1w[(size_t)col*1024 + kc]);
        acc[0][nt] = mfma(a0, b, acc[0][nt]);
        acc[1][nt] = mfma(a1, b, acc[1][nt]);
      }
    }
    #pragma unroll
    for (int nt = 0; nt < 2; ++nt){
      const int col = w*32 + nt*16 + ln;
      const float sc = sc2[col], sh = sh2[col];
      #pragma unroll
      for (int mt = 0; mt < 2; ++mt)
        #pragma unroll
        for (int e = 0; e < 4; ++e){
          float v = fmaxf(acc[mt][nt][e]*sc + sh, 0.f);
          actS[(mt*16 + lq*4 + e)*264 + col] = f2bf(v);
        }
    }
    __syncthreads();
  }

  if (w == 0){
    f4 acc[2] = {};
    for (int kt = 0; kt < 8; ++kt){
      const int kc = kt*32 + lq*8;
      bf8 a0 = ldb(&actS[ln*264 + kc]);
      bf8 a1 = ldb(&actS[(16 + ln)*264 + kc]);
      bf8 b  = ldb(&fc2wp[ln*256 + kc]);
      acc[0] = mfma(a0, b, acc[0]);
      acc[1] = mfma(a1, b, acc[1]);
    }
    const float bb = fc2b[ln];
    #pragma unroll
    for (int mt = 0; mt < 2; ++mt)
      #pragma unroll
      for (int e = 0; e < 4; ++e)
        lg[(mt*16 + lq*4 + e)*16 + ln] = acc[mt][e] + bb;
  }
  __syncthreads();
  if (tid < 32){
    const int r = tid;
    float mx = -1e30f;
    for (int cc = 0; cc < 10; ++cc) mx = fmaxf(mx, lg[r*16 + cc]);
    float sum = 0.f;
    for (int cc = 0; cc < 10; ++cc) sum += __expf(lg[r*16 + cc] - mx);
    const float lse = mx + logf(sum);
    for (int cc = 0; cc < 10; ++cc)
      out[(row0 + r)*10 + cc] = lg[r*16 + cc] - lse;
  }
}

// ---------------- cooperative launch helper ----------------
static void launch_chain(hipStream_t stream,
  const us* W, int Kw, int KX,
  const float* xbase, long xtstep, const us* gx4,
  us* hpp, float* hF,
  us* ybase, long ymstride, long ytstep,
  const float* brz, const float* bni, const float* bnh,
  int s0, int nsteps, unsigned int* flags)
{
  void* args[] = { &W, &Kw, &KX, &xbase, &xtstep, &gx4, &hpp, &hF,
                   &ybase, &ymstride, &ytstep, &brz, &bni, &bnh,
                   &s0, &nsteps, &flags };
  hipLaunchCooperativeKernel((void*)gru_chain_kernel, dim3(256), dim3(512),
                             args, 0, stream);
}

// ---------------- launch ----------------
extern "C" void kernel_launch(void* const* d_in, const int* in_sizes, int n_in,
                              void* d_out, int out_size, void* d_ws, size_t ws_size,
                              hipStream_t stream)
{
  (void)in_sizes; (void)n_in; (void)out_size; (void)ws_size;
  char* ws = (char*)d_ws;
  auto US = [&](size_t off){ return (us*)(ws + off); };
  auto FP = [&](size_t off){ return (float*)(ws + off); };

  const float* x      = (const float*)d_in[0];
  const float* Wih0   = (const float*)d_in[1];
  const float* Whh0   = (const float*)d_in[2];
  const float* bih0   = (const float*)d_in[3];
  const float* bhh0   = (const float*)d_in[4];
  const float* Wih0r  = (const float*)d_in[5];
  const float* Whh0r  = (const float*)d_in[6];
  const float* bih0r  = (const float*)d_in[7];
  const float* bhh0r  = (const float*)d_in[8];
  const float* Wih1   = (const float*)d_in[9];
  const float* Whh1   = (const float*)d_in[10];
  const float* bih1   = (const float*)d_in[11];
  const float* bhh1   = (const float*)d_in[12];
  const float* Wih1r  = (const float*)d_in[13];
  // d_in[14] (W_hh_l1r) unused: backward layer-1 runs exactly one step from h=0.
  const float* bih1r  = (const float*)d_in[15];
  const float* bhh1r  = (const float*)d_in[16];
  const float* fc1w   = (const float*)d_in[17];
  const float* fc1b   = (const float*)d_in[18];
  const float* gma    = (const float*)d_in[19];
  const float* bta    = (const float*)d_in[20];
  const float* mean   = (const float*)d_in[21];
  const float* var    = (const float*)d_in[22];
  const float* fc2w   = (const float*)d_in[23];
  const float* fc2b   = (const float*)d_in[24];

  unsigned int* flags = (unsigned int*)(ws + OFF_FLAGS);
  zeroflags_kernel<<<(NFLAGS + 255)/256, 256, 0, stream>>>(flags);

  prep_kernel<<<512, 256, 0, stream>>>(
    Wih0, Whh0, bih0, bhh0, Wih0r, Whh0r, bih0r, bhh0r,
    Wih1, Whh1, bih1, bhh1, Wih1r, bih1r, bhh1r,
    fc1w, fc1b, gma, bta, mean, var, fc2w, fc2b,
    US(OFF_WCAT0), US(OFF_WIH1), US(OFF_WHH1), US(OFF_WIH1R),
    US(OFF_FC1W), US(OFF_FC2W),
    FP(OFF_BRZ0), FP(OFF_BNIH0), FP(OFF_BNHH0),
    FP(OFF_BRZ1), FP(OFF_BNIH1), FP(OFF_BNHH1),
    FP(OFF_BRZ1R), FP(OFF_BNIH1R), FP(OFF_BNHH1R),
    FP(OFF_SC2), FP(OFF_SH2), FP(OFF_FC2B));

  us* y0b  = US(OFF_Y0B);
  us* y0fc = US(OFF_Y0FC);
  us* gx   = US(OFF_GX);
  us* h0bf = US(OFF_H0BF);
  us* h1bf = US(OFF_H1BF);

  unsigned int* fl0b = flags;            // chain 0: l0 backward, steps 0..27
  unsigned int* fl0f = flags + 28*16;    // chain 1: l0 forward
  unsigned int* fl1f = flags + 56*16;    // chain 2: l1 forward

  // ---- phase A: layer-0 backward, ONE 28-step chain launch ----
  launch_chain(stream,
    US(OFF_WCAT0) + 1536ll*544, 544, 32,
    x + 27*28, -28, nullptr,
    h0bf, FP(OFF_H0F32),
    y0b + 27ll*512, 28ll*512, -512,
    FP(OFF_BRZ0) + 1024, FP(OFF_BNIH0) + 512, FP(OFF_BNHH0) + 512,
    0, 28, fl0b);

  // ---- phase B: 7 x [l0f chain-4 -> gx1 GEMM -> l1f chain-4] ----
  for (int c = 0; c < 7; ++c){
    const int t0 = 4*c;
    launch_chain(stream,
      US(OFF_WCAT0), 544, 32,
      x + t0*28, 28, nullptr,
      h0bf, FP(OFF_H0F32),
      y0fc, 4ll*512, 512,
      FP(OFF_BRZ0), FP(OFF_BNIH0), FP(OFF_BNHH0),
      t0, 4, fl0f);

    gemm_kernel<<<128*12, 512, 0, stream>>>(
      y0fc, 4ll*512, 512, 512,
      y0b + (long)t0*512, 28ll*512, 512, 512,
      US(OFF_WIH1), 1024, 32, 2, 128, gx, PLANE);

    launch_chain(stream,
      US(OFF_WHH1), 512, 0,
      nullptr, 0, gx,
      h1bf, FP(OFF_H1F32),
      nullptr, 0, 0,
      FP(OFF_BRZ1), FP(OFF_BNIH1), FP(OFF_BNHH1),
      t0, 4, fl1f);
  }

  // ---- layer-1 backward: gxb = [h0f_27 | y0b_27] @ Wih1r^T, then gates (h=0) ----
  gemm_kernel<<<32*12, 512, 0, stream>>>(
    h0bf, 512, 0, 512,                       // h0f final state = pp plane 0
    y0b + 27ll*512, 28ll*512, 0, 512,
    US(OFF_WIH1R), 1024, 32, 0, 32, gx, 0);
  gate1b_kernel<<<8192, 256, 0, stream>>>(
    gx, FP(OFF_BRZ1R), FP(OFF_BNIH1R), FP(OFF_BNHH1R), US(OFF_H1B));

  // ---- head (h1f final = pp plane 0 after 28 steps) ----
  head_kernel<<<128, 512, 0, stream>>>(
    h1bf, US(OFF_H1B), US(OFF_FC1W), US(OFF_FC2W),
    FP(OFF_SC2), FP(OFF_SH2), FP(OFF_FC2B), (float*)d_out);
}